// Round 1
// baseline (271.309 us; speedup 1.0000x reference)
//
#include <hip/hip_runtime.h>
#include <hip/hip_bf16.h>

// out = (x @ R^T) @ codes^T + bias, where codes = codebook[indices]
// x: [32,4096] f32, indices: [8192,4096] i32(0..15), codebook:[16] f32,
// R: [4096,4096] f32, bias: [8192] f32, out: [32,8192] f32.
//
// K0: out = bias, y_ws = 0
// K1: y_ws[32,4096] += x @ R^T        (bf16 MFMA, K-split 8, fp32 atomics)
// K2: out[32,8192]  += y @ codes^T    (bf16 MFMA, K-split 4, fp32 atomics)

#define IN_F 4096
#define OUT_F 8192
#define BATCH 32
#define TSTRIDE 136   // LDS row stride in bf16 elems: 272 B = 17*16 B (conflict-free b128 frag reads)

typedef short bf16x8s __attribute__((ext_vector_type(8)));   // 8 bf16 in 4 VGPRs (guide-verified form)
typedef float f32x4 __attribute__((ext_vector_type(4)));

// fp32 -> bf16 bits, round-to-nearest-even (inputs are normal randn values)
__device__ __forceinline__ unsigned short f2bf(float f) {
    union { float f; unsigned int u; } v; v.f = f;
    unsigned int u = v.u;
    return (unsigned short)((u + 0x7fffu + ((u >> 16) & 1u)) >> 16);
}

// ---------------- K0: init out with bias, zero y scratch ----------------
__global__ void __launch_bounds__(256) init_kernel(const float* __restrict__ bias,
                                                   float* __restrict__ out,
                                                   float* __restrict__ y_ws) {
    int id = blockIdx.x * 256 + threadIdx.x;          // grid 1024 * 256 = 262144
    if (id < BATCH * OUT_F) out[id] = bias[id & (OUT_F - 1)];
    if (id < BATCH * IN_F)  y_ws[id] = 0.0f;
}

// ---------------- K1: y = x @ R^T (bf16 MFMA) ----------------
// grid = 64 j-tiles * 8 k-splits = 512 blocks, 256 threads (4 waves)
// block tile: M=32 (all batches) x N=64 j's x K=512
__global__ void __launch_bounds__(256) k1_xRT(const float* __restrict__ x,
                                              const float* __restrict__ R,
                                              float* __restrict__ y_ws) {
    __shared__ unsigned short Bl[64 * TSTRIDE];  // R tile  [64 j][128 k] bf16
    __shared__ unsigned short Al[32 * TSTRIDE];  // x tile  [32 b][128 k] bf16

    const int tid  = threadIdx.x;
    const int jt   = blockIdx.x & 63;     // j tile
    const int kq   = blockIdx.x >> 6;     // 0..7
    const int j0   = jt * 64;
    const int kbase = kq * 512;
    const int wave = tid >> 6, lane = tid & 63;
    const int n = lane & 15, quad = lane >> 4;

    f32x4 acc0 = {0.f, 0.f, 0.f, 0.f};
    f32x4 acc1 = {0.f, 0.f, 0.f, 0.f};

    for (int kc = 0; kc < 512; kc += 128) {
        const int k0 = kbase + kc;
        __syncthreads();   // previous chunk's compute done before overwrite

        // stage R tile: [64][128] f32 -> bf16 LDS. 2048 float4, 8 per thread.
        #pragma unroll
        for (int jj = 0; jj < 8; ++jj) {
            int f = tid + jj * 256;              // flat over [64 rows][32 float4]
            int row = f >> 5, c4 = f & 31;
            const float4 v = *(const float4*)(R + (size_t)(j0 + row) * IN_F + k0 + c4 * 4);
            ushort4 pv;
            pv.x = f2bf(v.x); pv.y = f2bf(v.y); pv.z = f2bf(v.z); pv.w = f2bf(v.w);
            *(ushort4*)&Bl[row * TSTRIDE + c4 * 4] = pv;
        }
        // stage x tile: [32][128] f32 -> bf16 LDS. 1024 float4, 4 per thread.
        #pragma unroll
        for (int ii = 0; ii < 4; ++ii) {
            int f = tid + ii * 256;              // flat over [32 rows][32 float4]
            int row = f >> 5, c4 = f & 31;
            const float4 v = *(const float4*)(x + (size_t)row * IN_F + k0 + c4 * 4);
            ushort4 pv;
            pv.x = f2bf(v.x); pv.y = f2bf(v.y); pv.z = f2bf(v.z); pv.w = f2bf(v.w);
            *(ushort4*)&Al[row * TSTRIDE + c4 * 4] = pv;
        }
        __syncthreads();

        // compute: wave handles n-tile [wave*16, +16), both m-tiles (b 0..15, 16..31)
        #pragma unroll
        for (int ks = 0; ks < 4; ++ks) {
            bf16x8s bfr = *(const bf16x8s*)&Bl[(wave * 16 + n) * TSTRIDE + ks * 32 + quad * 8];
            bf16x8s a0  = *(const bf16x8s*)&Al[n * TSTRIDE + ks * 32 + quad * 8];
            bf16x8s a1  = *(const bf16x8s*)&Al[(16 + n) * TSTRIDE + ks * 32 + quad * 8];
            acc0 = __builtin_amdgcn_mfma_f32_16x16x32_bf16(a0, bfr, acc0, 0, 0, 0);
            acc1 = __builtin_amdgcn_mfma_f32_16x16x32_bf16(a1, bfr, acc1, 0, 0, 0);
        }
    }

    // epilogue: C/D layout col=lane&15 (n), row=quad*4+r (m). K-split partials -> atomics.
    const int jcol = j0 + wave * 16 + n;
    #pragma unroll
    for (int r = 0; r < 4; ++r) {
        int br = quad * 4 + r;
        atomicAdd(&y_ws[(size_t)br * IN_F + jcol], acc0[r]);
        atomicAdd(&y_ws[(size_t)(br + 16) * IN_F + jcol], acc1[r]);
    }
}

// ---------------- K2: out += y @ codes^T (bf16 MFMA, fused dequant) ----------------
// grid = 128 o-tiles * 4 k-splits = 512 blocks, 256 threads (4 waves)
// block tile: M=32 x N=64 o's x K=1024
__global__ void __launch_bounds__(256) k2_out(const int* __restrict__ idx,
                                              const float* __restrict__ cb,
                                              const float* __restrict__ yws,
                                              float* __restrict__ out) {
    __shared__ unsigned short Bl[64 * TSTRIDE];  // codes tile [64 o][128 k] bf16
    __shared__ unsigned short Al[32 * TSTRIDE];  // y tile     [32 b][128 k] bf16
    __shared__ unsigned int cbp[256];            // pair table: (i,j) -> bf16(cb[i]) | bf16(cb[j])<<16

    const int tid = threadIdx.x;

    // build dequant pair table: one ds_read_b32 turns 2 indices into 2 packed bf16
    {
        unsigned int lo = f2bf(cb[tid & 15]);
        unsigned int hi = f2bf(cb[tid >> 4]);
        cbp[tid] = lo | (hi << 16);
    }

    const int ot = blockIdx.x & 127;      // o tile
    const int kq = blockIdx.x >> 7;       // 0..3
    const int o0 = ot * 64;
    const int kbase = kq * 1024;
    const int wave = tid >> 6, lane = tid & 63;
    const int n = lane & 15, quad = lane >> 4;

    f32x4 acc0 = {0.f, 0.f, 0.f, 0.f};
    f32x4 acc1 = {0.f, 0.f, 0.f, 0.f};

    for (int kc = 0; kc < 1024; kc += 128) {
        const int k0 = kbase + kc;
        __syncthreads();   // also covers table build on first iteration

        // stage codes tile: [64][128] indices -> bf16 LDS via pair table. 8 int4/thread.
        #pragma unroll
        for (int jj = 0; jj < 8; ++jj) {
            int f = tid + jj * 256;              // flat over [64 rows][32 int4]
            int row = f >> 5, c4 = f & 31;
            const int4 iv = *(const int4*)(idx + (size_t)(o0 + row) * IN_F + k0 + c4 * 4);
            unsigned int key0 = (unsigned int)iv.x | ((unsigned int)iv.y << 4);
            unsigned int key1 = (unsigned int)iv.z | ((unsigned int)iv.w << 4);
            uint2 pv;
            pv.x = cbp[key0];
            pv.y = cbp[key1];
            *(uint2*)&Bl[row * TSTRIDE + c4 * 4] = pv;
        }
        // stage y tile: [32][128] f32 -> bf16 LDS. 4 float4/thread.
        #pragma unroll
        for (int ii = 0; ii < 4; ++ii) {
            int f = tid + ii * 256;
            int row = f >> 5, c4 = f & 31;
            const float4 v = *(const float4*)(yws + (size_t)row * IN_F + k0 + c4 * 4);
            ushort4 pv;
            pv.x = f2bf(v.x); pv.y = f2bf(v.y); pv.z = f2bf(v.z); pv.w = f2bf(v.w);
            *(ushort4*)&Al[row * TSTRIDE + c4 * 4] = pv;
        }
        __syncthreads();

        #pragma unroll
        for (int ks = 0; ks < 4; ++ks) {
            bf16x8s bfr = *(const bf16x8s*)&Bl[(wave * 16 + n) * TSTRIDE + ks * 32 + quad * 8];
            bf16x8s a0  = *(const bf16x8s*)&Al[n * TSTRIDE + ks * 32 + quad * 8];
            bf16x8s a1  = *(const bf16x8s*)&Al[(16 + n) * TSTRIDE + ks * 32 + quad * 8];
            acc0 = __builtin_amdgcn_mfma_f32_16x16x32_bf16(a0, bfr, acc0, 0, 0, 0);
            acc1 = __builtin_amdgcn_mfma_f32_16x16x32_bf16(a1, bfr, acc1, 0, 0, 0);
        }
    }

    const int ocol = o0 + wave * 16 + n;
    #pragma unroll
    for (int r = 0; r < 4; ++r) {
        int br = quad * 4 + r;
        atomicAdd(&out[(size_t)br * OUT_F + ocol], acc0[r]);
        atomicAdd(&out[(size_t)(br + 16) * OUT_F + ocol], acc1[r]);
    }
}

extern "C" void kernel_launch(void* const* d_in, const int* in_sizes, int n_in,
                              void* d_out, int out_size, void* d_ws, size_t ws_size,
                              hipStream_t stream) {
    (void)in_sizes; (void)n_in; (void)out_size; (void)ws_size;
    const float* x       = (const float*)d_in[0];
    const int*   indices = (const int*)d_in[1];
    const float* cb      = (const float*)d_in[2];
    const float* R       = (const float*)d_in[3];
    const float* bias    = (const float*)d_in[4];
    float* out  = (float*)d_out;
    float* y_ws = (float*)d_ws;           // 32*4096 f32 = 512 KB scratch

    init_kernel<<<dim3(1024), dim3(256), 0, stream>>>(bias, out, y_ws);
    k1_xRT   <<<dim3(512),  dim3(256), 0, stream>>>(x, R, y_ws);
    k2_out   <<<dim3(512),  dim3(256), 0, stream>>>(indices, cb, y_ws, out);
}

// Round 2
// 255.853 us; speedup vs baseline: 1.0604x; 1.0604x over previous
//
#include <hip/hip_runtime.h>
#include <hip/hip_bf16.h>

// out = (x @ R^T) @ codes^T + bias, where codes = codebook[indices]
// x: [32,4096] f32, indices: [8192,4096] i32(0..15), codebook:[16] f32,
// R: [4096,4096] f32, bias: [8192] f32, out: [32,8192] f32.
//
// K0: out = bias, y_ws = 0
// K1: y_ws[32,4096] += x @ R^T        (bf16 MFMA, ksplit 8, 2x256-chunk, fp32 atomics)
// K2: out[32,8192]  += y @ codes^T    (bf16 MFMA, ksplit 8, 2x256-chunk, fp32 atomics)

#define IN_F 4096
#define OUT_F 8192
#define BATCH 32
#define TS 264   // LDS row stride in bf16 elems: 528 B (132 words, +4-bank row rotation)

typedef short bf16x8s __attribute__((ext_vector_type(8)));   // 8 bf16 in 4 VGPRs
typedef float f32x4 __attribute__((ext_vector_type(4)));

// fp32 -> bf16 bits, round-to-nearest-even
__device__ __forceinline__ unsigned short f2bf(float f) {
    union { float f; unsigned int u; } v; v.f = f;
    unsigned int u = v.u;
    return (unsigned short)((u + 0x7fffu + ((u >> 16) & 1u)) >> 16);
}

// ---------------- K0: init out with bias, zero y scratch ----------------
__global__ void __launch_bounds__(256) init_kernel(const float* __restrict__ bias,
                                                   float* __restrict__ out,
                                                   float* __restrict__ y_ws) {
    int id = blockIdx.x * 256 + threadIdx.x;          // grid 1024 * 256 = 262144
    if (id < BATCH * OUT_F) out[id] = bias[id & (OUT_F - 1)];
    if (id < BATCH * IN_F)  y_ws[id] = 0.0f;
}

// ---------------- K1: y = x @ R^T (bf16 MFMA) ----------------
// grid = 64 j-tiles * 8 k-splits = 512 blocks, 256 threads (4 waves)
// block tile: M=32 x N=64 j x K=512 (2 chunks of 256)
__global__ void __launch_bounds__(256, 2) k1_xRT(const float* __restrict__ x,
                                                 const float* __restrict__ R,
                                                 float* __restrict__ y_ws) {
    __shared__ unsigned short Bl[64 * TS];  // R tile  [64 j][256 k] bf16
    __shared__ unsigned short Al[32 * TS];  // x tile  [32 b][256 k] bf16

    const int tid  = threadIdx.x;
    const int jt   = blockIdx.x & 63;
    const int kq   = blockIdx.x >> 6;     // 0..7
    const int j0   = jt * 64;
    const int kbase = kq * 512;
    const int wave = tid >> 6, lane = tid & 63;
    const int n = lane & 15, quad = lane >> 4;

    f32x4 acc0 = {0.f, 0.f, 0.f, 0.f};
    f32x4 acc1 = {0.f, 0.f, 0.f, 0.f};

    for (int kc = 0; kc < 2; ++kc) {
        const int k0 = kbase + kc * 256;
        __syncthreads();   // previous chunk's compute done before overwrite

        // stage R tile: [64][256] f32 -> bf16. 4096 float4, 16/thread.
        #pragma unroll
        for (int jj = 0; jj < 16; ++jj) {
            int f = tid + jj * 256;              // [64 rows][64 float4]
            int row = f >> 6, c4 = f & 63;
            const float4 v = *(const float4*)(R + (size_t)(j0 + row) * IN_F + k0 + c4 * 4);
            ushort4 pv;
            pv.x = f2bf(v.x); pv.y = f2bf(v.y); pv.z = f2bf(v.z); pv.w = f2bf(v.w);
            *(ushort4*)&Bl[row * TS + c4 * 4] = pv;
        }
        // stage x tile: [32][256] f32 -> bf16. 2048 float4, 8/thread.
        #pragma unroll
        for (int ii = 0; ii < 8; ++ii) {
            int f = tid + ii * 256;              // [32 rows][64 float4]
            int row = f >> 6, c4 = f & 63;
            const float4 v = *(const float4*)(x + (size_t)row * IN_F + k0 + c4 * 4);
            ushort4 pv;
            pv.x = f2bf(v.x); pv.y = f2bf(v.y); pv.z = f2bf(v.z); pv.w = f2bf(v.w);
            *(ushort4*)&Al[row * TS + c4 * 4] = pv;
        }
        __syncthreads();

        #pragma unroll
        for (int ks = 0; ks < 8; ++ks) {
            bf16x8s bfr = *(const bf16x8s*)&Bl[(wave * 16 + n) * TS + ks * 32 + quad * 8];
            bf16x8s a0  = *(const bf16x8s*)&Al[n * TS + ks * 32 + quad * 8];
            bf16x8s a1  = *(const bf16x8s*)&Al[(16 + n) * TS + ks * 32 + quad * 8];
            acc0 = __builtin_amdgcn_mfma_f32_16x16x32_bf16(a0, bfr, acc0, 0, 0, 0);
            acc1 = __builtin_amdgcn_mfma_f32_16x16x32_bf16(a1, bfr, acc1, 0, 0, 0);
        }
    }

    // C/D layout: col=lane&15 (n), row=quad*4+r (m)
    const int jcol = j0 + wave * 16 + n;
    #pragma unroll
    for (int r = 0; r < 4; ++r) {
        int br = quad * 4 + r;
        atomicAdd(&y_ws[(size_t)br * IN_F + jcol], acc0[r]);
        atomicAdd(&y_ws[(size_t)(br + 16) * IN_F + jcol], acc1[r]);
    }
}

// ---------------- K2: out += y @ codes^T (bf16 MFMA, fused dequant) ----------------
// grid = 128 o-tiles * 8 k-splits = 1024 blocks, 256 threads (4 waves)
// block tile: M=32 x N=64 o x K=512 (2 chunks of 256)
__global__ void __launch_bounds__(256, 3) k2_out(const int* __restrict__ idx,
                                                 const float* __restrict__ cb,
                                                 const float* __restrict__ yws,
                                                 float* __restrict__ out) {
    __shared__ unsigned short Bl[64 * TS];  // codes tile [64 o][256 k] bf16
    __shared__ unsigned short Al[32 * TS];  // y tile     [32 b][256 k] bf16
    __shared__ unsigned int cbp[256];       // pair table: (i,j) -> bf16(cb[i]) | bf16(cb[j])<<16

    const int tid = threadIdx.x;

    // build dequant pair table: one ds_read_b32 turns 2 indices into 2 packed bf16
    {
        unsigned int lo = f2bf(cb[tid & 15]);
        unsigned int hi = f2bf(cb[tid >> 4]);
        cbp[tid] = lo | (hi << 16);
    }

    const int ot = blockIdx.x & 127;
    const int kq = blockIdx.x >> 7;       // 0..7
    const int o0 = ot * 64;
    const int kbase = kq * 512;
    const int wave = tid >> 6, lane = tid & 63;
    const int n = lane & 15, quad = lane >> 4;

    f32x4 acc0 = {0.f, 0.f, 0.f, 0.f};
    f32x4 acc1 = {0.f, 0.f, 0.f, 0.f};

    for (int kc = 0; kc < 2; ++kc) {
        const int k0 = kbase + kc * 256;
        __syncthreads();   // covers table build on first iteration, LDS reuse after

        // stage codes tile: [64][256] indices -> bf16 via pair table. 4096 int4, 16/thread.
        #pragma unroll
        for (int jj = 0; jj < 16; ++jj) {
            int f = tid + jj * 256;              // [64 rows][64 int4]
            int row = f >> 6, c4 = f & 63;
            const int4 iv = *(const int4*)(idx + (size_t)(o0 + row) * IN_F + k0 + c4 * 4);
            unsigned int key0 = (unsigned int)iv.x | ((unsigned int)iv.y << 4);
            unsigned int key1 = (unsigned int)iv.z | ((unsigned int)iv.w << 4);
            uint2 pv;
            pv.x = cbp[key0];
            pv.y = cbp[key1];
            *(uint2*)&Bl[row * TS + c4 * 4] = pv;
        }
        // stage y tile: [32][256] f32 -> bf16. 2048 float4, 8/thread.
        #pragma unroll
        for (int ii = 0; ii < 8; ++ii) {
            int f = tid + ii * 256;
            int row = f >> 6, c4 = f & 63;
            const float4 v = *(const float4*)(yws + (size_t)row * IN_F + k0 + c4 * 4);
            ushort4 pv;
            pv.x = f2bf(v.x); pv.y = f2bf(v.y); pv.z = f2bf(v.z); pv.w = f2bf(v.w);
            *(ushort4*)&Al[row * TS + c4 * 4] = pv;
        }
        __syncthreads();

        #pragma unroll
        for (int ks = 0; ks < 8; ++ks) {
            bf16x8s bfr = *(const bf16x8s*)&Bl[(wave * 16 + n) * TS + ks * 32 + quad * 8];
            bf16x8s a0  = *(const bf16x8s*)&Al[n * TS + ks * 32 + quad * 8];
            bf16x8s a1  = *(const bf16x8s*)&Al[(16 + n) * TS + ks * 32 + quad * 8];
            acc0 = __builtin_amdgcn_mfma_f32_16x16x32_bf16(a0, bfr, acc0, 0, 0, 0);
            acc1 = __builtin_amdgcn_mfma_f32_16x16x32_bf16(a1, bfr, acc1, 0, 0, 0);
        }
    }

    const int ocol = o0 + wave * 16 + n;
    #pragma unroll
    for (int r = 0; r < 4; ++r) {
        int br = quad * 4 + r;
        atomicAdd(&out[(size_t)br * OUT_F + ocol], acc0[r]);
        atomicAdd(&out[(size_t)(br + 16) * OUT_F + ocol], acc1[r]);
    }
}

extern "C" void kernel_launch(void* const* d_in, const int* in_sizes, int n_in,
                              void* d_out, int out_size, void* d_ws, size_t ws_size,
                              hipStream_t stream) {
    (void)in_sizes; (void)n_in; (void)out_size; (void)ws_size;
    const float* x       = (const float*)d_in[0];
    const int*   indices = (const int*)d_in[1];
    const float* cb      = (const float*)d_in[2];
    const float* R       = (const float*)d_in[3];
    const float* bias    = (const float*)d_in[4];
    float* out  = (float*)d_out;
    float* y_ws = (float*)d_ws;           // 32*4096 f32 = 512 KB scratch

    init_kernel<<<dim3(1024), dim3(256), 0, stream>>>(bias, out, y_ws);
    k1_xRT   <<<dim3(512),  dim3(256), 0, stream>>>(x, R, y_ws);
    k2_out   <<<dim3(1024), dim3(256), 0, stream>>>(indices, cb, y_ws, out);
}

// Round 3
// 250.956 us; speedup vs baseline: 1.0811x; 1.0195x over previous
//
#include <hip/hip_runtime.h>
#include <hip/hip_bf16.h>

// out = (x @ R^T) @ codes^T + bias, where codes = codebook[indices]
// x: [32,4096] f32, indices: [8192,4096] i32(0..15), codebook:[16] f32,
// R: [4096,4096] f32, bias: [8192] f32, out: [32,8192] f32.
//
// memset: y_ws = 0 (512 KB)
// K1: out = bias (prologue) ; y_ws[32,4096] += x @ R^T   (bf16 MFMA, ksplit 16, single 256-chunk)
// K2: out[32,8192] += y @ codes^T                        (bf16 MFMA, ksplit 16, single 256-chunk)

#define IN_F 4096
#define OUT_F 8192
#define BATCH 32
#define TS 264   // LDS row stride in bf16 elems: 528 B (132 words; 132 % 32 == 4 -> rotated b128 frags)

typedef short bf16x8s __attribute__((ext_vector_type(8)));   // 8 bf16 in 4 VGPRs
typedef float f32x4 __attribute__((ext_vector_type(4)));

// fp32 -> bf16 bits, round-to-nearest-even
__device__ __forceinline__ unsigned short f2bf(float f) {
    union { float f; unsigned int u; } v; v.f = f;
    unsigned int u = v.u;
    return (unsigned short)((u + 0x7fffu + ((u >> 16) & 1u)) >> 16);
}

// ---------------- K1: y = x @ R^T (bf16 MFMA), out=bias prologue ----------------
// grid = 64 j-tiles * 16 k-splits = 1024 blocks, 256 threads (4 waves)
// block tile: M=32 x N=64 j x K=256 (single chunk, one barrier)
__global__ void __launch_bounds__(256, 3) k1_xRT(const float* __restrict__ x,
                                                 const float* __restrict__ R,
                                                 const float* __restrict__ bias,
                                                 float* __restrict__ out,
                                                 float* __restrict__ y_ws) {
    __shared__ unsigned short Bl[64 * TS];  // R tile  [64 j][256 k] bf16
    __shared__ unsigned short Al[32 * TS];  // x tile  [32 b][256 k] bf16

    const int tid  = threadIdx.x;
    const int jt   = blockIdx.x & 63;
    const int kq   = blockIdx.x >> 6;     // 0..15
    const int j0   = jt * 64;
    const int k0   = kq * 256;
    const int wave = tid >> 6, lane = tid & 63;
    const int n = lane & 15, quad = lane >> 4;

    // out = bias init: 262144 elems over 1024 blocks = 1/thread (before K2's atomics)
    {
        int id = blockIdx.x * 256 + tid;
        out[id] = bias[id & (OUT_F - 1)];
    }

    // stage R tile: [64][256] f32 -> bf16. 4096 float4, 16/thread.
    #pragma unroll
    for (int jj = 0; jj < 16; ++jj) {
        int f = tid + jj * 256;              // [64 rows][64 float4]
        int row = f >> 6, c4 = f & 63;
        const float4 v = *(const float4*)(R + (size_t)(j0 + row) * IN_F + k0 + c4 * 4);
        ushort4 pv;
        pv.x = f2bf(v.x); pv.y = f2bf(v.y); pv.z = f2bf(v.z); pv.w = f2bf(v.w);
        *(ushort4*)&Bl[row * TS + c4 * 4] = pv;
    }
    // stage x tile: [32][256] f32 -> bf16. 2048 float4, 8/thread.
    #pragma unroll
    for (int ii = 0; ii < 8; ++ii) {
        int f = tid + ii * 256;              // [32 rows][64 float4]
        int row = f >> 6, c4 = f & 63;
        const float4 v = *(const float4*)(x + (size_t)row * IN_F + k0 + c4 * 4);
        ushort4 pv;
        pv.x = f2bf(v.x); pv.y = f2bf(v.y); pv.z = f2bf(v.z); pv.w = f2bf(v.w);
        *(ushort4*)&Al[row * TS + c4 * 4] = pv;
    }
    __syncthreads();

    f32x4 acc0 = {0.f, 0.f, 0.f, 0.f};
    f32x4 acc1 = {0.f, 0.f, 0.f, 0.f};
    #pragma unroll
    for (int ks = 0; ks < 8; ++ks) {
        bf16x8s bfr = *(const bf16x8s*)&Bl[(wave * 16 + n) * TS + ks * 32 + quad * 8];
        bf16x8s a0  = *(const bf16x8s*)&Al[n * TS + ks * 32 + quad * 8];
        bf16x8s a1  = *(const bf16x8s*)&Al[(16 + n) * TS + ks * 32 + quad * 8];
        acc0 = __builtin_amdgcn_mfma_f32_16x16x32_bf16(a0, bfr, acc0, 0, 0, 0);
        acc1 = __builtin_amdgcn_mfma_f32_16x16x32_bf16(a1, bfr, acc1, 0, 0, 0);
    }

    // C/D layout: col=lane&15 (n), row=quad*4+r (m)
    const int jcol = j0 + wave * 16 + n;
    #pragma unroll
    for (int r = 0; r < 4; ++r) {
        int br = quad * 4 + r;
        atomicAdd(&y_ws[(size_t)br * IN_F + jcol], acc0[r]);
        atomicAdd(&y_ws[(size_t)(br + 16) * IN_F + jcol], acc1[r]);
    }
}

// ---------------- K2: out += y @ codes^T (bf16 MFMA, fused dequant) ----------------
// grid = 128 o-tiles * 16 k-splits = 2048 blocks, 256 threads (4 waves)
// block tile: M=32 x N=64 o x K=256 (single chunk)
__global__ void __launch_bounds__(256, 3) k2_out(const int* __restrict__ idx,
                                                 const float* __restrict__ cb,
                                                 const float* __restrict__ yws,
                                                 float* __restrict__ out) {
    __shared__ unsigned short Bl[64 * TS];  // codes tile [64 o][256 k] bf16
    __shared__ unsigned short Al[32 * TS];  // y tile     [32 b][256 k] bf16
    __shared__ unsigned int cbp[256];       // pair table: (i,j) -> bf16(cb[i]) | bf16(cb[j])<<16

    const int tid = threadIdx.x;

    // build dequant pair table: one ds_read_b32 turns 2 indices into 2 packed bf16
    {
        unsigned int lo = f2bf(cb[tid & 15]);
        unsigned int hi = f2bf(cb[tid >> 4]);
        cbp[tid] = lo | (hi << 16);
    }

    const int ot = blockIdx.x & 127;
    const int kq = blockIdx.x >> 7;       // 0..15
    const int o0 = ot * 64;
    const int k0 = kq * 256;
    const int wave = tid >> 6, lane = tid & 63;
    const int n = lane & 15, quad = lane >> 4;

    __syncthreads();   // cbp table visible to all staging threads

    // stage codes tile: [64][256] indices -> bf16 via pair table. 4096 int4, 16/thread.
    #pragma unroll
    for (int jj = 0; jj < 16; ++jj) {
        int f = tid + jj * 256;              // [64 rows][64 int4]
        int row = f >> 6, c4 = f & 63;
        const int4 iv = *(const int4*)(idx + (size_t)(o0 + row) * IN_F + k0 + c4 * 4);
        unsigned int key0 = (unsigned int)iv.x | ((unsigned int)iv.y << 4);
        unsigned int key1 = (unsigned int)iv.z | ((unsigned int)iv.w << 4);
        uint2 pv;
        pv.x = cbp[key0];
        pv.y = cbp[key1];
        *(uint2*)&Bl[row * TS + c4 * 4] = pv;
    }
    // stage y tile: [32][256] f32 -> bf16. 2048 float4, 8/thread.
    #pragma unroll
    for (int ii = 0; ii < 8; ++ii) {
        int f = tid + ii * 256;
        int row = f >> 6, c4 = f & 63;
        const float4 v = *(const float4*)(yws + (size_t)row * IN_F + k0 + c4 * 4);
        ushort4 pv;
        pv.x = f2bf(v.x); pv.y = f2bf(v.y); pv.z = f2bf(v.z); pv.w = f2bf(v.w);
        *(ushort4*)&Al[row * TS + c4 * 4] = pv;
    }
    __syncthreads();

    f32x4 acc0 = {0.f, 0.f, 0.f, 0.f};
    f32x4 acc1 = {0.f, 0.f, 0.f, 0.f};
    #pragma unroll
    for (int ks = 0; ks < 8; ++ks) {
        bf16x8s bfr = *(const bf16x8s*)&Bl[(wave * 16 + n) * TS + ks * 32 + quad * 8];
        bf16x8s a0  = *(const bf16x8s*)&Al[n * TS + ks * 32 + quad * 8];
        bf16x8s a1  = *(const bf16x8s*)&Al[(16 + n) * TS + ks * 32 + quad * 8];
        acc0 = __builtin_amdgcn_mfma_f32_16x16x32_bf16(a0, bfr, acc0, 0, 0, 0);
        acc1 = __builtin_amdgcn_mfma_f32_16x16x32_bf16(a1, bfr, acc1, 0, 0, 0);
    }

    const int ocol = o0 + wave * 16 + n;
    #pragma unroll
    for (int r = 0; r < 4; ++r) {
        int br = quad * 4 + r;
        atomicAdd(&out[(size_t)br * OUT_F + ocol], acc0[r]);
        atomicAdd(&out[(size_t)(br + 16) * OUT_F + ocol], acc1[r]);
    }
}

extern "C" void kernel_launch(void* const* d_in, const int* in_sizes, int n_in,
                              void* d_out, int out_size, void* d_ws, size_t ws_size,
                              hipStream_t stream) {
    (void)in_sizes; (void)n_in; (void)out_size; (void)ws_size;
    const float* x       = (const float*)d_in[0];
    const int*   indices = (const int*)d_in[1];
    const float* cb      = (const float*)d_in[2];
    const float* R       = (const float*)d_in[3];
    const float* bias    = (const float*)d_in[4];
    float* out  = (float*)d_out;
    float* y_ws = (float*)d_ws;           // 32*4096 f32 = 512 KB scratch

    hipMemsetAsync(y_ws, 0, (size_t)BATCH * IN_F * sizeof(float), stream);
    k1_xRT<<<dim3(1024), dim3(256), 0, stream>>>(x, R, bias, out, y_ws);
    k2_out<<<dim3(2048), dim3(256), 0, stream>>>(indices, cb, y_ws, out);
}

// Round 4
// 238.797 us; speedup vs baseline: 1.1361x; 1.0509x over previous
//
#include <hip/hip_runtime.h>
#include <hip/hip_bf16.h>

// out = (x @ R^T) @ codes^T + bias, where codes = codebook[indices]
// x: [32,4096] f32, indices: [8192,4096] i32(0..15), codebook:[16] f32,
// R: [4096,4096] f32, bias: [8192] f32, out: [32,8192] f32.
//
// memset: y_ws = 0 (512 KB)
// K1: out = bias (prologue) ; y_ws += x @ R^T   (bf16 MFMA, ksplit 16, front-loaded vmem)
// K2: out += y @ codes^T                        (bf16 MFMA, ksplit 16, front-loaded vmem)

#define IN_F 4096
#define OUT_F 8192
#define BATCH 32
#define TS 264   // LDS row stride in bf16 elems: 528 B = 33*16 B (16B-aligned rows, bank-rotated)

typedef short bf16x8s __attribute__((ext_vector_type(8)));   // 8 bf16 in 4 VGPRs
typedef float f32x4 __attribute__((ext_vector_type(4)));
typedef int   i32x4 __attribute__((ext_vector_type(4)));

// fp32 -> bf16 bits, round-to-nearest-even
__device__ __forceinline__ unsigned short f2bf(float f) {
    union { float f; unsigned int u; } v; v.f = f;
    unsigned int u = v.u;
    return (unsigned short)((u + 0x7fffu + ((u >> 16) & 1u)) >> 16);
}

// ---------------- K1: y = x @ R^T (bf16 MFMA), out=bias prologue ----------------
// grid = 64 j-tiles * 16 k-splits = 1024 blocks, 256 threads (4 waves)
__global__ void __launch_bounds__(256, 3) k1_xRT(const float* __restrict__ x,
                                                 const float* __restrict__ R,
                                                 const float* __restrict__ bias,
                                                 float* __restrict__ out,
                                                 float* __restrict__ y_ws) {
    __shared__ unsigned short Bl[64 * TS];  // R tile  [64 j][256 k] bf16
    __shared__ unsigned short Al[32 * TS];  // x tile  [32 b][256 k] bf16

    const int tid  = threadIdx.x;
    const int jt   = blockIdx.x & 63;
    const int kq   = blockIdx.x >> 6;     // 0..15
    const int j0   = jt * 64;
    const int k0   = kq * 256;
    const int wave = tid >> 6, lane = tid & 63;
    const int n = lane & 15, quad = lane >> 4;

    // ---- issue ALL global loads first (R is stream-once -> nontemporal) ----
    f32x4 rv[16];
    #pragma unroll
    for (int jj = 0; jj < 16; ++jj) {
        int f = tid + jj * 256;              // [64 rows][64 float4]
        int row = f >> 6, c4 = f & 63;
        rv[jj] = __builtin_nontemporal_load(
            (const f32x4*)(R + (size_t)(j0 + row) * IN_F + k0 + c4 * 4));
    }
    f32x4 xv[8];
    #pragma unroll
    for (int ii = 0; ii < 8; ++ii) {
        int f = tid + ii * 256;              // [32 rows][64 float4]
        int row = f >> 6, c4 = f & 63;
        xv[ii] = *(const f32x4*)(x + (size_t)row * IN_F + k0 + c4 * 4);
    }
    // out = bias init: 262144 elems over 1024 blocks = 1/thread (before K2's atomics)
    {
        int id = blockIdx.x * 256 + tid;
        out[id] = bias[id & (OUT_F - 1)];
    }

    // ---- convert + LDS write ----
    #pragma unroll
    for (int jj = 0; jj < 16; ++jj) {
        int f = tid + jj * 256;
        int row = f >> 6, c4 = f & 63;
        ushort4 pv;
        pv.x = f2bf(rv[jj].x); pv.y = f2bf(rv[jj].y);
        pv.z = f2bf(rv[jj].z); pv.w = f2bf(rv[jj].w);
        *(ushort4*)&Bl[row * TS + c4 * 4] = pv;
    }
    #pragma unroll
    for (int ii = 0; ii < 8; ++ii) {
        int f = tid + ii * 256;
        int row = f >> 6, c4 = f & 63;
        ushort4 pv;
        pv.x = f2bf(xv[ii].x); pv.y = f2bf(xv[ii].y);
        pv.z = f2bf(xv[ii].z); pv.w = f2bf(xv[ii].w);
        *(ushort4*)&Al[row * TS + c4 * 4] = pv;
    }
    __syncthreads();

    f32x4 acc0 = {0.f, 0.f, 0.f, 0.f};
    f32x4 acc1 = {0.f, 0.f, 0.f, 0.f};
    #pragma unroll
    for (int ks = 0; ks < 8; ++ks) {
        bf16x8s bfr = *(const bf16x8s*)&Bl[(wave * 16 + n) * TS + ks * 32 + quad * 8];
        bf16x8s a0  = *(const bf16x8s*)&Al[n * TS + ks * 32 + quad * 8];
        bf16x8s a1  = *(const bf16x8s*)&Al[(16 + n) * TS + ks * 32 + quad * 8];
        acc0 = __builtin_amdgcn_mfma_f32_16x16x32_bf16(a0, bfr, acc0, 0, 0, 0);
        acc1 = __builtin_amdgcn_mfma_f32_16x16x32_bf16(a1, bfr, acc1, 0, 0, 0);
    }

    // C/D layout: col=lane&15 (n), row=quad*4+r (m)
    const int jcol = j0 + wave * 16 + n;
    #pragma unroll
    for (int r = 0; r < 4; ++r) {
        int br = quad * 4 + r;
        atomicAdd(&y_ws[(size_t)br * IN_F + jcol], acc0[r]);
        atomicAdd(&y_ws[(size_t)(br + 16) * IN_F + jcol], acc1[r]);
    }
}

// ---------------- K2: out += y @ codes^T (bf16 MFMA, fused dequant) ----------------
// grid = 128 o-tiles * 16 k-splits = 2048 blocks, 256 threads (4 waves)
__global__ void __launch_bounds__(256, 3) k2_out(const int* __restrict__ idx,
                                                 const float* __restrict__ cb,
                                                 const float* __restrict__ yws,
                                                 float* __restrict__ out) {
    __shared__ unsigned short Bl[64 * TS];  // codes tile [64 o][256 k] bf16
    __shared__ unsigned short Al[32 * TS];  // y tile     [32 b][256 k] bf16
    __shared__ unsigned int cbp[256];       // pair table: (i,j) -> bf16(cb[i]) | bf16(cb[j])<<16

    const int tid = threadIdx.x;
    const int ot = blockIdx.x & 127;
    const int kq = blockIdx.x >> 7;       // 0..15
    const int o0 = ot * 64;
    const int k0 = kq * 256;
    const int wave = tid >> 6, lane = tid & 63;
    const int n = lane & 15, quad = lane >> 4;

    // ---- issue ALL global loads first (idx is stream-once -> nontemporal) ----
    i32x4 iv[16];
    #pragma unroll
    for (int jj = 0; jj < 16; ++jj) {
        int f = tid + jj * 256;              // [64 rows][64 int4]
        int row = f >> 6, c4 = f & 63;
        iv[jj] = __builtin_nontemporal_load(
            (const i32x4*)(idx + (size_t)(o0 + row) * IN_F + k0 + c4 * 4));
    }
    f32x4 fv[8];
    #pragma unroll
    for (int ii = 0; ii < 8; ++ii) {
        int f = tid + ii * 256;              // [32 rows][64 float4]
        int row = f >> 6, c4 = f & 63;
        fv[ii] = *(const f32x4*)(yws + (size_t)row * IN_F + k0 + c4 * 4);
    }

    // dequant pair table (loads overlap the barrier below)
    {
        unsigned int lo = f2bf(cb[tid & 15]);
        unsigned int hi = f2bf(cb[tid >> 4]);
        cbp[tid] = lo | (hi << 16);
    }
    __syncthreads();   // cbp visible; idx/y loads still in flight

    // ---- convert + LDS write ----
    #pragma unroll
    for (int jj = 0; jj < 16; ++jj) {
        int f = tid + jj * 256;
        int row = f >> 6, c4 = f & 63;
        unsigned int key0 = (unsigned int)iv[jj].x | ((unsigned int)iv[jj].y << 4);
        unsigned int key1 = (unsigned int)iv[jj].z | ((unsigned int)iv[jj].w << 4);
        uint2 pv;
        pv.x = cbp[key0];
        pv.y = cbp[key1];
        *(uint2*)&Bl[row * TS + c4 * 4] = pv;
    }
    #pragma unroll
    for (int ii = 0; ii < 8; ++ii) {
        int f = tid + ii * 256;
        int row = f >> 6, c4 = f & 63;
        ushort4 pv;
        pv.x = f2bf(fv[ii].x); pv.y = f2bf(fv[ii].y);
        pv.z = f2bf(fv[ii].z); pv.w = f2bf(fv[ii].w);
        *(ushort4*)&Al[row * TS + c4 * 4] = pv;
    }
    __syncthreads();

    f32x4 acc0 = {0.f, 0.f, 0.f, 0.f};
    f32x4 acc1 = {0.f, 0.f, 0.f, 0.f};
    #pragma unroll
    for (int ks = 0; ks < 8; ++ks) {
        bf16x8s bfr = *(const bf16x8s*)&Bl[(wave * 16 + n) * TS + ks * 32 + quad * 8];
        bf16x8s a0  = *(const bf16x8s*)&Al[n * TS + ks * 32 + quad * 8];
        bf16x8s a1  = *(const bf16x8s*)&Al[(16 + n) * TS + ks * 32 + quad * 8];
        acc0 = __builtin_amdgcn_mfma_f32_16x16x32_bf16(a0, bfr, acc0, 0, 0, 0);
        acc1 = __builtin_amdgcn_mfma_f32_16x16x32_bf16(a1, bfr, acc1, 0, 0, 0);
    }

    const int ocol = o0 + wave * 16 + n;
    #pragma unroll
    for (int r = 0; r < 4; ++r) {
        int br = quad * 4 + r;
        atomicAdd(&out[(size_t)br * OUT_F + ocol], acc0[r]);
        atomicAdd(&out[(size_t)(br + 16) * OUT_F + ocol], acc1[r]);
    }
}

extern "C" void kernel_launch(void* const* d_in, const int* in_sizes, int n_in,
                              void* d_out, int out_size, void* d_ws, size_t ws_size,
                              hipStream_t stream) {
    (void)in_sizes; (void)n_in; (void)out_size; (void)ws_size;
    const float* x       = (const float*)d_in[0];
    const int*   indices = (const int*)d_in[1];
    const float* cb      = (const float*)d_in[2];
    const float* R       = (const float*)d_in[3];
    const float* bias    = (const float*)d_in[4];
    float* out  = (float*)d_out;
    float* y_ws = (float*)d_ws;           // 32*4096 f32 = 512 KB scratch

    hipMemsetAsync(y_ws, 0, (size_t)BATCH * IN_F * sizeof(float), stream);
    k1_xRT<<<dim3(1024), dim3(256), 0, stream>>>(x, R, bias, out, y_ws);
    k2_out<<<dim3(2048), dim3(256), 0, stream>>>(indices, cb, y_ws, out);
}